// Round 4
// baseline (429.607 us; speedup 1.0000x reference)
//
#include <hip/hip_runtime.h>

typedef unsigned short u16;
typedef __attribute__((ext_vector_type(4))) u16 u16x4;
typedef __attribute__((ext_vector_type(8))) __bf16 bf16x8;
typedef __attribute__((ext_vector_type(4))) float f32x4;

#define B_ 2
#define T_ 2048
#define DIM_ 2048
#define NH_ 16
#define HD_ 128

__device__ __forceinline__ u16 f2b(float f) {
  unsigned u = __builtin_bit_cast(unsigned, f);
  u += 0x7fffu + ((u >> 16) & 1u);
  return (u16)(u >> 16);
}
__device__ __forceinline__ float b2f(u16 h) {
  unsigned u = ((unsigned)h) << 16;
  return __builtin_bit_cast(float, u);
}
__device__ __forceinline__ unsigned pack2(float lo, float hi) {
  return (unsigned)f2b(lo) | ((unsigned)f2b(hi) << 16);
}

typedef __attribute__((address_space(1))) void gvoid_t;
typedef __attribute__((address_space(3))) void lvoid_t;
__device__ __forceinline__ void gload16(const void* g, void* l) {
  __builtin_amdgcn_global_load_lds((gvoid_t*)g, (lvoid_t*)l, 16, 0, 0);
}

// ---------------- fp32 -> bf16 conversion (x + 4 weights) ----------------
__global__ __launch_bounds__(256) void cvt_bf16(const float* x, const float* wq,
    const float* wk, const float* wv, const float* wo,
    u16* xb, u16* wqb, u16* wkb, u16* wvb, u16* wob) {
  int ten = blockIdx.y;
  const float* s; u16* d; int n4;
  if (ten == 0)      { s = x;  d = xb;  n4 = 2097152; }
  else if (ten == 1) { s = wq; d = wqb; n4 = 1048576; }
  else if (ten == 2) { s = wk; d = wkb; n4 = 1048576; }
  else if (ten == 3) { s = wv; d = wvb; n4 = 1048576; }
  else               { s = wo; d = wob; n4 = 1048576; }
  int i = blockIdx.x * 256 + threadIdx.x;
  if (i >= n4) return;
  float4 f = ((const float4*)s)[i];
  u16x4 o = { f2b(f.x), f2b(f.y), f2b(f.z), f2b(f.w) };
  ((u16x4*)d)[i] = o;
}

// ------- GEMM C[M,N] = A[M,K] B[N,K]^T; BK=32 double-buffered, 1 barrier/iter.
// Stage(it+1) issued right after the barrier -> its vmcnt drain happens at the
// NEXT barrier, a full compute-iteration later (no exposed stall).
// LDS 16B-chunk swizzle slot = c ^ ((r + r>>2)&3): frag reads hit all 8 bank
// groups 2x (free per m136). Optional fused RoPE in the epilogue (rotate cols
// j<32 with j+32 partners -- both live in the same wave's acc regs nb/nb+2).
template <typename OutT>
__device__ __forceinline__ void gemm_body(const u16* A, const u16* Bw, OutT* C,
                                          int row0, int col0, int rotate, int scaleQ) {
  constexpr int K = 2048, N = 2048;
  __shared__ u16 As[2][128 * 32];
  __shared__ u16 Bs[2][128 * 32];
  const int tid = threadIdx.x;
  const int w = tid >> 6, l = tid & 63, n = l & 15, quad = l >> 4;
  const int r = tid >> 2, cl = tid & 3;
  const int cg = cl ^ ((r + (r >> 2)) & 3);
  const u16* aP = A + (size_t)(row0 + r) * K + cg * 8;
  const u16* bP = Bw + (size_t)(col0 + r) * K + cg * 8;
  const int ldst = tid * 8;   // u16 offset == tid*16 bytes (wave-uniform + lane*16)
  auto stage = [&](int kt, int buf) {
    gload16(aP + kt, As[buf] + ldst);
    gload16(aP + kt + (size_t)64 * K, As[buf] + 2048 + ldst);
    gload16(bP + kt, Bs[buf] + ldst);
    gload16(bP + kt + (size_t)64 * K, Bs[buf] + 2048 + ldst);
  };
  const int wr0 = (w >> 1) * 64, wc0 = (w & 1) * 64;
  const int fsl = (quad ^ ((n + (n >> 2)) & 3)) * 8;
  f32x4 acc[4][4] = {};
  stage(0, 0);
  for (int kt = 0; kt < K; kt += 32) {
    const int buf = (kt >> 5) & 1;
    __syncthreads();                       // stage(kt) drained; prev buf reads done
    if (kt + 32 < K) stage(kt + 32, buf ^ 1);
    bf16x8 af[4], bfr[4];
#pragma unroll
    for (int mb = 0; mb < 4; ++mb)
      af[mb] = *(const bf16x8*)&As[buf][(wr0 + mb * 16 + n) * 32 + fsl];
#pragma unroll
    for (int nb = 0; nb < 4; ++nb)
      bfr[nb] = *(const bf16x8*)&Bs[buf][(wc0 + nb * 16 + n) * 32 + fsl];
#pragma unroll
    for (int mb = 0; mb < 4; ++mb)
#pragma unroll
      for (int nb = 0; nb < 4; ++nb)
        acc[mb][nb] = __builtin_amdgcn_mfma_f32_16x16x32_bf16(af[mb], bfr[nb], acc[mb][nb], 0, 0, 0);
  }

  // ---- fused RoPE (tile cols == one head; cols 0..63 in the wc0==0 wave) ----
  if (rotate && wc0 == 0) {
#pragma unroll
    for (int nb = 0; nb < 2; ++nb) {
      int j = nb * 16 + n;                       // j in [0,32)
      double f1 = exp2(-(double)j * 0.20762050593045951);  // log2(10000)/64
      double f2 = f1 * 0.01;                     // freq of j+32
      const double INV2PI = 0.15915494309189535;
#pragma unroll
      for (int mb = 0; mb < 4; ++mb)
#pragma unroll
        for (int rr = 0; rr < 4; ++rr) {
          int t = (row0 + wr0 + mb * 16 + quad * 4 + rr) & (T_ - 1);
          double a1 = (double)t * f1 * INV2PI; a1 -= floor(a1);
          double a2 = (double)t * f2 * INV2PI; a2 -= floor(a2);
          float c1 = __builtin_amdgcn_cosf((float)a1), s1 = __builtin_amdgcn_sinf((float)a1);
          float c2 = __builtin_amdgcn_cosf((float)a2), s2 = __builtin_amdgcn_sinf((float)a2);
          float x1 = acc[mb][nb][rr], x2 = acc[mb][nb + 2][rr];
          acc[mb][nb][rr]     = x1 * c1 - x2 * s1;
          acc[mb][nb + 2][rr] = x2 * c2 + x1 * s2;
        }
    }
  }
  const float osc = scaleQ ? 0.12751743342408354f : 1.0f;  // log2(e)/sqrt(128)

#pragma unroll
  for (int mb = 0; mb < 4; ++mb)
#pragma unroll
    for (int nb = 0; nb < 4; ++nb)
#pragma unroll
      for (int rr = 0; rr < 4; ++rr) {
        size_t idx = (size_t)(row0 + wr0 + mb * 16 + quad * 4 + rr) * N + (col0 + wc0 + nb * 16 + n);
        float v = acc[mb][nb][rr] * osc;
        if constexpr (sizeof(OutT) == 2) C[idx] = f2b(v); else C[idx] = v;
      }
}

__global__ __launch_bounds__(256, 3) void gemm_qkv(const u16* A, const u16* w0, const u16* w1,
    const u16* w2, u16* c0, u16* c1, u16* c2) {
  const int z = blockIdx.z;
  const u16* Bw = (z == 0) ? w0 : (z == 1) ? w1 : w2;
  u16* C = (z == 0) ? c0 : (z == 1) ? c1 : c2;
  gemm_body<u16>(A, Bw, C, blockIdx.y * 128, blockIdx.x * 128, z < 2, z == 0);
}
__global__ __launch_bounds__(256, 3) void gemm_o(const u16* A, const u16* Bw, float* C) {
  gemm_body<float>(A, Bw, C, blockIdx.y * 128, blockIdx.x * 128, 0, 0);
}

// ---------------- V transpose per batch: Vt[b][c][t] = V[b][t][c] ----------------
__global__ __launch_bounds__(256) void transpose_v(const u16* V, u16* Vt) {
  int b = blockIdx.z;
  int t0 = blockIdx.x * 64, c0 = blockIdx.y * 64;
  __shared__ u16 tile[64][72];
  int tid = threadIdx.x;
#pragma unroll
  for (int i = 0; i < 4; ++i) {
    int v = i * 256 + tid;
    int r = v >> 4, c4 = (v & 15) * 4;
    *(u16x4*)&tile[r][c4] = *(const u16x4*)(V + (size_t)(b * T_ + t0 + r) * DIM_ + c0 + c4);
  }
  __syncthreads();
#pragma unroll
  for (int i = 0; i < 4; ++i) {
    int v = i * 256 + tid;
    int d = v >> 4, t4 = (v & 15) * 4;
    u16x4 o = { tile[t4 + 0][d], tile[t4 + 1][d], tile[t4 + 2][d], tile[t4 + 3][d] };
    *(u16x4*)(Vt + (size_t)(b * DIM_ + c0 + d) * T_ + t0 + t4) = o;
  }
}

// ---------------- flash attention (transposed; BK=64; K,V double-buffered) ------
__global__ __launch_bounds__(256, 2) void attn_k(const u16* Q, const u16* K, const u16* Vt, u16* Y) {
  const int qt = blockIdx.x, bh = blockIdx.y;
  const int b = bh >> 4, h = bh & 15;
  const int tid = threadIdx.x;
  const int w = tid >> 6, l = tid & 63, n = l & 15, quad = l >> 4;
  __shared__ u16 Ks[2][64 * 128];   // [k-row][hd]
  __shared__ u16 Vs[2][128 * 64];   // [d-row][t]

  const u16* Qbase = Q + (size_t)(b * T_ + qt * 128 + w * 32) * DIM_ + h * HD_;
  const u16* Kbase = K + (size_t)(b * T_) * DIM_ + h * HD_;
  const u16* Vbase = Vt + (size_t)(b * DIM_ + h * HD_) * T_;

  bf16x8 qf[2][4];
#pragma unroll
  for (int qtile = 0; qtile < 2; ++qtile)
#pragma unroll
    for (int ks = 0; ks < 4; ++ks)
      qf[qtile][ks] = *(const bf16x8*)(Qbase + (size_t)(qtile * 16 + n) * DIM_ + ks * 32 + quad * 8);

  auto stageK = [&](int itn, u16* dst) {   // 64 rows x 128 hd (16 chunks/row)
#pragma unroll
    for (int inst = 0; inst < 4; ++inst) {
      int ci = inst * 256 + w * 64 + l;
      int r = ci >> 4, cl = ci & 15;
      int cg = cl ^ (r & 7);
      gload16(Kbase + (size_t)(itn * 64 + r) * DIM_ + cg * 8, (char*)dst + (inst * 256 + w * 64) * 16);
    }
  };
  auto stageV = [&](int itn, u16* dst) {   // 128 rows x 64 t (8 chunks/row)
#pragma unroll
    for (int inst = 0; inst < 4; ++inst) {
      int ci = inst * 256 + w * 64 + l;
      int r = ci >> 3, cl = ci & 7;
      int cg = cl ^ (r & 7);
      gload16(Vbase + (size_t)r * T_ + itn * 64 + cg * 8, (char*)dst + (inst * 256 + w * 64) * 16);
    }
  };

  f32x4 o[2][8] = {};
  float m_r[2] = { -__builtin_inff(), -__builtin_inff() };
  float l_r[2] = { 0.f, 0.f };

  const int shA = ((quad & 1) * 2) * 16 + n;
  const int shB = shA + 16;
  const bool hiTile = (quad >= 2);

  auto iter_body = [&](const u16* Kc, const u16* Vc, u16* Kn, u16* Vn, int itn) {
    __syncthreads();
    if (itn >= 0) { stageK(itn, Kn); stageV(itn, Vn); }

    f32x4 st[2][4] = {};
#pragma unroll
    for (int ks = 0; ks < 4; ++ks) {
      bf16x8 kf[4];
#pragma unroll
      for (int mt = 0; mt < 4; ++mt)
        kf[mt] = *(const bf16x8*)&Kc[(mt * 16 + n) * 128 + (((ks * 4 + quad) ^ (n & 7)) * 8)];
#pragma unroll
      for (int qtile = 0; qtile < 2; ++qtile)
#pragma unroll
        for (int mt = 0; mt < 4; ++mt)
          st[qtile][mt] = __builtin_amdgcn_mfma_f32_16x16x32_bf16(kf[mt], qf[qtile][ks], st[qtile][mt], 0, 0, 0);
    }

    unsigned pk[2][4][2];
#pragma unroll
    for (int qtile = 0; qtile < 2; ++qtile) {
      float mx = -__builtin_inff();
#pragma unroll
      for (int mt = 0; mt < 4; ++mt)
#pragma unroll
        for (int r2 = 0; r2 < 4; ++r2) mx = fmaxf(mx, st[qtile][mt][r2]);
      mx = fmaxf(mx, __shfl_xor(mx, 16, 64));
      mx = fmaxf(mx, __shfl_xor(mx, 32, 64));
      float mo = m_r[qtile];
      float mn = fmaxf(mo, mx);
      float al = __builtin_amdgcn_exp2f(mo - mn);
      float rs = 0.f;
#pragma unroll
      for (int mt = 0; mt < 4; ++mt)
#pragma unroll
        for (int r2 = 0; r2 < 4; ++r2) {
          float p = __builtin_amdgcn_exp2f(st[qtile][mt][r2] - mn);
          st[qtile][mt][r2] = p;
          rs += p;
        }
      rs += __shfl_xor(rs, 16, 64);
      rs += __shfl_xor(rs, 32, 64);
      l_r[qtile] = al * l_r[qtile] + rs;
      m_r[qtile] = mn;
#pragma unroll
      for (int mt = 0; mt < 4; ++mt) {
        pk[qtile][mt][0] = pack2(st[qtile][mt][0], st[qtile][mt][1]);
        pk[qtile][mt][1] = pack2(st[qtile][mt][2], st[qtile][mt][3]);
      }
#pragma unroll
      for (int mt = 0; mt < 8; ++mt)
#pragma unroll
        for (int r2 = 0; r2 < 4; ++r2) o[qtile][mt][r2] *= al;
    }

    typedef __attribute__((ext_vector_type(4))) unsigned uint4v;
    uint4v pT[2][2];
#pragma unroll
    for (int qtile = 0; qtile < 2; ++qtile)
#pragma unroll
      for (int ks2 = 0; ks2 < 2; ++ks2)
#pragma unroll
        for (int jj = 0; jj < 4; ++jj) {
          int src = (jj < 2) ? shA : shB;
          unsigned vA = __shfl((int)pk[qtile][ks2 * 2][jj & 1], src, 64);
          unsigned vB = __shfl((int)pk[qtile][ks2 * 2 + 1][jj & 1], src, 64);
          pT[qtile][ks2][jj] = hiTile ? vB : vA;
        }

#pragma unroll
    for (int ks2 = 0; ks2 < 2; ++ks2) {
      bf16x8 vf[8];
#pragma unroll
      for (int mt = 0; mt < 8; ++mt)
        vf[mt] = *(const bf16x8*)&Vc[(mt * 16 + n) * 64 + (((ks2 * 4 + quad) ^ (n & 7)) * 8)];
#pragma unroll
      for (int qtile = 0; qtile < 2; ++qtile) {
        bf16x8 pfrag = __builtin_bit_cast(bf16x8, pT[qtile][ks2]);
#pragma unroll
        for (int mt = 0; mt < 8; ++mt)
          o[qtile][mt] = __builtin_amdgcn_mfma_f32_16x16x32_bf16(vf[mt], pfrag, o[qtile][mt], 0, 0, 0);
      }
    }
  };

  stageK(0, Ks[0]); stageV(0, Vs[0]);
  for (int it = 0; it < 32; it += 2) {
    iter_body(Ks[0], Vs[0], Ks[1], Vs[1], it + 1);
    iter_body(Ks[1], Vs[1], Ks[0], Vs[0], (it + 2 < 32) ? it + 2 : -1);
  }

  u16* Ybase = Y + (size_t)(b * T_ + qt * 128 + w * 32) * DIM_ + h * HD_;
#pragma unroll
  for (int qtile = 0; qtile < 2; ++qtile) {
    float inv = 1.0f / l_r[qtile];
#pragma unroll
    for (int mt = 0; mt < 8; ++mt) {
      u16x4 ov = { f2b(o[qtile][mt][0] * inv), f2b(o[qtile][mt][1] * inv),
                   f2b(o[qtile][mt][2] * inv), f2b(o[qtile][mt][3] * inv) };
      *(u16x4*)(Ybase + (size_t)(qtile * 16 + n) * DIM_ + mt * 16 + quad * 4) = ov;
    }
  }
}

extern "C" void kernel_launch(void* const* d_in, const int* in_sizes, int n_in,
                              void* d_out, int out_size, void* d_ws, size_t ws_size,
                              hipStream_t stream) {
  const float* x  = (const float*)d_in[0];
  const float* wq = (const float*)d_in[1];
  const float* wk = (const float*)d_in[2];
  const float* wv = (const float*)d_in[3];
  const float* wo = (const float*)d_in[4];

  u16* ws  = (u16*)d_ws;
  u16* xb  = ws;                   // 8388608
  u16* wqb = xb + 8388608;         // 4194304 each
  u16* wkb = wqb + 4194304;
  u16* wvb = wkb + 4194304;
  u16* wob = wvb + 4194304;
  u16* qb  = wob + 4194304;        // 8388608 each
  u16* kb  = qb + 8388608;
  u16* vb  = kb + 8388608;
  u16* vt  = vb + 8388608;
  u16* yb  = vt + 8388608;         // total 128 MiB

  cvt_bf16<<<dim3(8192, 5), 256, 0, stream>>>(x, wq, wk, wv, wo, xb, wqb, wkb, wvb, wob);
  gemm_qkv<<<dim3(16, 32, 3), 256, 0, stream>>>(xb, wqb, wkb, wvb, qb, kb, vb);
  transpose_v<<<dim3(32, 32, 2), 256, 0, stream>>>(vb, vt);
  attn_k<<<dim3(16, 32), 256, 0, stream>>>(qb, kb, vt, yb);
  gemm_o<<<dim3(16, 32), 256, 0, stream>>>(yb, wob, (float*)d_out);
}